// Round 9
// baseline (160.615 us; speedup 1.0000x reference)
//
#include <hip/hip_runtime.h>

#define N_SEQ 4096
#define N_FFT 8192
#define LAYERS 3
#define FT 512                 // threads per FFT block
#define PIDX(i) ((i) + ((i) >> 5))   // +1 word per 32 -> all passes 2-way (free)

// =============== radix-16 pass: two DIF stages (M then M/4) in registers ===============
template<int M>
__device__ inline void pass16_fwd(float* re, float* im, int tid)
{
    const int Q = M >> 4;
    const int j = tid & (Q - 1);
    const int G = tid / Q;
    const int base = G * M + j;
    const float KR[4] = {1.f, 0.9238795325f, 0.7071067812f, 0.3826834324f};
    const float KI[4] = {0.f, -0.3826834324f, -0.7071067812f, -0.9238795325f};
    float xr[4][4], xi[4][4];
#pragma unroll
    for (int a = 0; a < 4; ++a)
#pragma unroll
        for (int b = 0; b < 4; ++b) {
            int idx = PIDX(base + a * (M >> 2) + b * Q);
            xr[a][b] = re[idx]; xi[a][b] = im[idx];
        }
    float cj, sj;
    __sincosf(-6.283185307179586f / (float)M * (float)j, &sj, &cj);
#pragma unroll
    for (int b = 0; b < 4; ++b) {
        float c1 = cj * KR[b] - sj * KI[b];
        float s1 = cj * KI[b] + sj * KR[b];
        float c2 = c1 * c1 - s1 * s1, s2 = 2.f * c1 * s1;
        float c3 = c2 * c1 - s2 * s1, s3 = c2 * s1 + s2 * c1;
        float ar = xr[0][b] + xr[2][b], ai = xi[0][b] + xi[2][b];
        float br = xr[0][b] - xr[2][b], bi = xi[0][b] - xi[2][b];
        float cr = xr[1][b] + xr[3][b], ci = xi[1][b] + xi[3][b];
        float dr = xi[1][b] - xi[3][b], di = -(xr[1][b] - xr[3][b]);
        xr[0][b] = ar + cr;               xi[0][b] = ai + ci;
        float t1r = br + dr, t1i = bi + di;
        xr[1][b] = t1r * c1 - t1i * s1;   xi[1][b] = t1r * s1 + t1i * c1;
        float t2r = ar - cr, t2i = ai - ci;
        xr[2][b] = t2r * c2 - t2i * s2;   xi[2][b] = t2r * s2 + t2i * c2;
        float t3r = br - dr, t3i = bi - di;
        xr[3][b] = t3r * c3 - t3i * s3;   xi[3][b] = t3r * s3 + t3i * c3;
    }
    {
        float e1c = cj * cj - sj * sj, e1s = 2.f * cj * sj;      // W^{2j}
        float c1 = e1c * e1c - e1s * e1s, s1 = 2.f * e1c * e1s;  // W^{4j}
        float c2 = c1 * c1 - s1 * s1, s2 = 2.f * c1 * s1;
        float c3 = c2 * c1 - s2 * s1, s3 = c2 * s1 + s2 * c1;
#pragma unroll
        for (int a = 0; a < 4; ++a) {
            float ar = xr[a][0] + xr[a][2], ai = xi[a][0] + xi[a][2];
            float br = xr[a][0] - xr[a][2], bi = xi[a][0] - xi[a][2];
            float cr = xr[a][1] + xr[a][3], ci = xi[a][1] + xi[a][3];
            float dr = xi[a][1] - xi[a][3], di = -(xr[a][1] - xr[a][3]);
            xr[a][0] = ar + cr;               xi[a][0] = ai + ci;
            float t1r = br + dr, t1i = bi + di;
            xr[a][1] = t1r * c1 - t1i * s1;   xi[a][1] = t1r * s1 + t1i * c1;
            float t2r = ar - cr, t2i = ai - ci;
            xr[a][2] = t2r * c2 - t2i * s2;   xi[a][2] = t2r * s2 + t2i * c2;
            float t3r = br - dr, t3i = bi - di;
            xr[a][3] = t3r * c3 - t3i * s3;   xi[a][3] = t3r * s3 + t3i * c3;
        }
    }
#pragma unroll
    for (int a = 0; a < 4; ++a)
#pragma unroll
        for (int b = 0; b < 4; ++b) {
            int idx = PIDX(base + a * (M >> 2) + b * Q);
            re[idx] = xr[a][b]; im[idx] = xi[a][b];
        }
}

template<int M>
__device__ inline void pass16_inv(float* re, float* im, int tid)
{
    const int Q = M >> 4;
    const int j = tid & (Q - 1);
    const int G = tid / Q;
    const int base = G * M + j;
    const float KR[4] = {1.f, 0.9238795325f, 0.7071067812f, 0.3826834324f};
    const float KI[4] = {0.f, 0.3826834324f, 0.7071067812f, 0.9238795325f};   // conj
    float xr[4][4], xi[4][4];
#pragma unroll
    for (int a = 0; a < 4; ++a)
#pragma unroll
        for (int b = 0; b < 4; ++b) {
            int idx = PIDX(base + a * (M >> 2) + b * Q);
            xr[a][b] = re[idx]; xi[a][b] = im[idx];
        }
    float cj, sj;
    __sincosf(6.283185307179586f / (float)M * (float)j, &sj, &cj);
    {
        float e1c = cj * cj - sj * sj, e1s = 2.f * cj * sj;
        float c1 = e1c * e1c - e1s * e1s, s1 = 2.f * e1c * e1s;
        float c2 = c1 * c1 - s1 * s1, s2 = 2.f * c1 * s1;
        float c3 = c2 * c1 - s2 * s1, s3 = c2 * s1 + s2 * c1;
#pragma unroll
        for (int a = 0; a < 4; ++a) {
            float t0r = xr[a][0], t0i = xi[a][0];
            float t1r = xr[a][1] * c1 - xi[a][1] * s1, t1i = xr[a][1] * s1 + xi[a][1] * c1;
            float t2r = xr[a][2] * c2 - xi[a][2] * s2, t2i = xr[a][2] * s2 + xi[a][2] * c2;
            float t3r = xr[a][3] * c3 - xi[a][3] * s3, t3i = xr[a][3] * s3 + xi[a][3] * c3;
            float pr = t0r + t2r, pi = t0i + t2i;
            float qr = t0r - t2r, qi = t0i - t2i;
            float rr = t1r + t3r, ri = t1i + t3i;
            float sr = -(t1i - t3i), si = t1r - t3r;
            xr[a][0] = pr + rr; xi[a][0] = pi + ri;
            xr[a][1] = qr + sr; xi[a][1] = qi + si;
            xr[a][2] = pr - rr; xi[a][2] = pi - ri;
            xr[a][3] = qr - sr; xi[a][3] = qi - si;
        }
    }
#pragma unroll
    for (int b = 0; b < 4; ++b) {
        float c1 = cj * KR[b] - sj * KI[b];
        float s1 = cj * KI[b] + sj * KR[b];
        float c2 = c1 * c1 - s1 * s1, s2 = 2.f * c1 * s1;
        float c3 = c2 * c1 - s2 * s1, s3 = c2 * s1 + s2 * c1;
        float t0r = xr[0][b], t0i = xi[0][b];
        float t1r = xr[1][b] * c1 - xi[1][b] * s1, t1i = xr[1][b] * s1 + xi[1][b] * c1;
        float t2r = xr[2][b] * c2 - xi[2][b] * s2, t2i = xr[2][b] * s2 + xi[2][b] * c2;
        float t3r = xr[3][b] * c3 - xi[3][b] * s3, t3i = xr[3][b] * s3 + xi[3][b] * c3;
        float pr = t0r + t2r, pi = t0i + t2i;
        float qr = t0r - t2r, qi = t0i - t2i;
        float rr = t1r + t3r, ri = t1i + t3i;
        float sr = -(t1i - t3i), si = t1r - t3r;
        xr[0][b] = pr + rr; xi[0][b] = pi + ri;
        xr[1][b] = qr + sr; xi[1][b] = qi + si;
        xr[2][b] = pr - rr; xi[2][b] = pi - ri;
        xr[3][b] = qr - sr; xi[3][b] = qi - si;
    }
#pragma unroll
    for (int a = 0; a < 4; ++a)
#pragma unroll
        for (int b = 0; b < 4; ++b) {
            int idx = PIDX(base + a * (M >> 2) + b * Q);
            re[idx] = xr[a][b]; im[idx] = xi[a][b];
        }
}

// ======= radix-8 tail (stage m=8 + r2), contiguous 8 points, constant twiddles =======
__device__ inline void fwd8(float* zr, float* zi, int o)
{
    const float R = 0.70710678118654752f;
    {
        float ar = zr[o] + zr[o+4], ai = zi[o] + zi[o+4];
        float br = zr[o] - zr[o+4], bi = zi[o] - zi[o+4];
        float cr = zr[o+2] + zr[o+6], ci = zi[o+2] + zi[o+6];
        float dr = zi[o+2] - zi[o+6], di = -(zr[o+2] - zr[o+6]);
        zr[o]   = ar + cr; zi[o]   = ai + ci;
        zr[o+2] = br + dr; zi[o+2] = bi + di;
        zr[o+4] = ar - cr; zi[o+4] = ai - ci;
        zr[o+6] = br - dr; zi[o+6] = bi - di;
    }
    {
        float ar = zr[o+1] + zr[o+5], ai = zi[o+1] + zi[o+5];
        float br = zr[o+1] - zr[o+5], bi = zi[o+1] - zi[o+5];
        float cr = zr[o+3] + zr[o+7], ci = zi[o+3] + zi[o+7];
        float dr = zi[o+3] - zi[o+7], di = -(zr[o+3] - zr[o+7]);
        zr[o+1] = ar + cr; zi[o+1] = ai + ci;
        float t1r = br + dr, t1i = bi + di;
        zr[o+3] = R * (t1r + t1i); zi[o+3] = R * (t1i - t1r);
        float t2r = ar - cr, t2i = ai - ci;
        zr[o+5] = t2i;  zi[o+5] = -t2r;
        float t3r = br - dr, t3i = bi - di;
        zr[o+7] = R * (t3i - t3r); zi[o+7] = -R * (t3r + t3i);
    }
#pragma unroll
    for (int p = 0; p < 8; p += 2) {
        float ur = zr[o+p], ui = zi[o+p], vr = zr[o+p+1], vi = zi[o+p+1];
        zr[o+p]   = ur + vr; zi[o+p]   = ui + vi;
        zr[o+p+1] = ur - vr; zi[o+p+1] = ui - vi;
    }
}

__device__ inline void inv8(float* zr, float* zi, int o)
{
    const float R = 0.70710678118654752f;
#pragma unroll
    for (int p = 0; p < 8; p += 2) {
        float ur = zr[o+p], ui = zi[o+p], vr = zr[o+p+1], vi = zi[o+p+1];
        zr[o+p]   = ur + vr; zi[o+p]   = ui + vi;
        zr[o+p+1] = ur - vr; zi[o+p+1] = ui - vi;
    }
    {
        float t0r = zr[o],   t0i = zi[o];
        float t1r = zr[o+2], t1i = zi[o+2];
        float t2r = zr[o+4], t2i = zi[o+4];
        float t3r = zr[o+6], t3i = zi[o+6];
        float pr = t0r + t2r, pi = t0i + t2i;
        float qr = t0r - t2r, qi = t0i - t2i;
        float rr = t1r + t3r, ri = t1i + t3i;
        float sr = -(t1i - t3i), si = t1r - t3r;
        zr[o]   = pr + rr; zi[o]   = pi + ri;
        zr[o+2] = qr + sr; zi[o+2] = qi + si;
        zr[o+4] = pr - rr; zi[o+4] = pi - ri;
        zr[o+6] = qr - sr; zi[o+6] = qi - si;
    }
    {
        float t0r = zr[o+1], t0i = zi[o+1];
        float yr = zr[o+3], yi = zi[o+3];
        float t1r = R * (yr - yi), t1i = R * (yr + yi);
        yr = zr[o+5]; yi = zi[o+5];
        float t2r = -yi, t2i = yr;
        yr = zr[o+7]; yi = zi[o+7];
        float t3r = -R * (yr + yi), t3i = R * (yr - yi);
        float pr = t0r + t2r, pi = t0i + t2i;
        float qr = t0r - t2r, qi = t0i - t2i;
        float rr = t1r + t3r, ri = t1i + t3i;
        float sr = -(t1i - t3i), si = t1r - t3r;
        zr[o+1] = pr + rr; zi[o+1] = pi + ri;
        zr[o+3] = qr + sr; zi[o+3] = qi + si;
        zr[o+5] = pr - rr; zi[o+5] = pi - ri;
        zr[o+7] = qr - sr; zi[o+7] = qi - si;
    }
}

// ============ prep: [blocks 0..127] RPE, lane=position + SGPR weights -> a_t
//              [blocks 128..639] transpose x -> xt2 ============
// LESSON (R6-R8 post-mortems): a CU has 4 SIMDs of VALU but ONE LDS pipe.
// Prior prep variants pushed weights AND activations through LDS -> ~38us
// LDS-pipe-bound regardless of tiling. Here: lane = position, wave = feature
// slice; ALL weight/bias addresses are lane-uniform (readfirstlane on wave id)
// -> scalar s_load path (SMEM pipe) + v_fmac with SGPR operand. LDS carries
// only the per-j activation broadcast (1 conflict-free ds_read_b32 per j) and
// the RMS partial-sum exchange. Out phase: wave = chunk c, acc[64] VGPRs,
// 64 fma per ds_read -> VALU-bound. Chip VALU floor ~4.7us.
__global__ __launch_bounds__(512, 4) void prep_kernel(
    const float* __restrict__ x,
    const float* __restrict__ w_in, const float* __restrict__ b_in,
    const float* __restrict__ w_hid, const float* __restrict__ b_hid,
    const float* __restrict__ w_out, const float* __restrict__ b_out,
    float* __restrict__ a_t, float2* __restrict__ xt2)
{
    __shared__ __align__(16) char smem[33536];
    const int tid = threadIdx.x;

    if (blockIdx.x >= 128) {
        // ---- transpose x: (2,8,N,64) -> xt2[hd][n] = (x_b0, x_b1) ----
        float (*t0)[65] = (float (*)[65])smem;
        float (*t1)[65] = (float (*)[65])(smem + 16640);
        int bb = blockIdx.x - 128;
        int h = bb >> 6;
        int nb = bb & 63;
        int lx = tid & 63;
        int ly = tid >> 6;          // 0..7
        const float* s0 = x + ((size_t)h * N_SEQ + nb * 64) * 64;
        const float* s1 = x + ((size_t)(8 + h) * N_SEQ + nb * 64) * 64;
        for (int r = ly; r < 64; r += 8) {
            t0[r][lx] = s0[r * 64 + lx];
            t1[r][lx] = s1[r * 64 + lx];
        }
        __syncthreads();
        for (int r = ly; r < 64; r += 8) {
            float2* dst = xt2 + (size_t)(h * 64 + r) * N_SEQ + nb * 64;
            dst[lx] = make_float2(t0[lx][r], t1[lx][r]);
        }
        return;
    }

    // ---- RPE: 64 positions/block (lane = pos), 8 waves = 8 feature-octets ----
    float (*ubuf)[65] = (float (*)[65])smem;               // [pos][feat] 16640 B
    float (*sums)[9]  = (float (*)[9])(smem + 16640);      // [pos][wave]  2304 B
    const int p = tid & 63;
    const int w = __builtin_amdgcn_readfirstlane(tid >> 6);   // wave id, SGPR
    const int pos = blockIdx.x * 64 + p;

    float v;
    if (pos == 0 || pos == N_SEQ) v = 1.0f;
    else if (pos < N_SEQ)         v = 1.0f / (float)(pos + 1);
    else                          v = -1.0f / (float)(2 * N_SEQ + 1 - pos);

    float h[8];
#pragma unroll
    for (int i = 0; i < 8; ++i) {
        int f = w * 8 + i;                 // lane-uniform -> s_load
        h[i] = v * w_in[f] + b_in[f];
    }
    for (int L = 0; L < LAYERS; ++L) {
        float s = 0.f;
#pragma unroll
        for (int i = 0; i < 8; ++i) s += h[i] * h[i];
        sums[p][w] = s;
        __syncthreads();                    // also: prior j-loop's ubuf reads done
        float tot = 0.f;
#pragma unroll
        for (int g = 0; g < 8; ++g) tot += sums[p][g];
        float r = rsqrtf(tot * (1.f / 64.f) + 1e-8f);
#pragma unroll
        for (int i = 0; i < 8; ++i)
            ubuf[p][w * 8 + i] = fmaxf(h[i] * r, 0.f);
        __syncthreads();
        float acc[8];
        const float* bh = b_hid + L * 64 + w * 8;   // uniform
#pragma unroll
        for (int i = 0; i < 8; ++i) acc[i] = bh[i];
        const float* wbase = w_hid + L * 4096 + w * 8;
        for (int j = 0; j < 64; ++j) {
            float uj = ubuf[p][j];          // per-lane, banks (p+j)%32: 2-way free
            const float* wr = wbase + j * 64;   // uniform row -> s_load
#pragma unroll
            for (int i = 0; i < 8; ++i)
                acc[i] = fmaf(uj, wr[i], acc[i]);
        }
#pragma unroll
        for (int i = 0; i < 8; ++i) h[i] = acc[i];
    }
    {   // final RMS + relu -> ubuf
        float s = 0.f;
#pragma unroll
        for (int i = 0; i < 8; ++i) s += h[i] * h[i];
        sums[p][w] = s;
        __syncthreads();
        float tot = 0.f;
#pragma unroll
        for (int g = 0; g < 8; ++g) tot += sums[p][g];
        float r = rsqrtf(tot * (1.f / 64.f) + 1e-8f);
#pragma unroll
        for (int i = 0; i < 8; ++i)
            ubuf[p][w * 8 + i] = fmaxf(h[i] * r, 0.f);
        __syncthreads();
    }
    // ---- out phase: wave = chunk c (64 outputs), acc in VGPRs, w via SGPR ----
    {
        const int c = w;
        float acc[64];
        const float* bo = b_out + c * 64;   // uniform
#pragma unroll
        for (int f = 0; f < 64; ++f) acc[f] = bo[f];
        const float* wbase = w_out + c * 64;
        for (int j = 0; j < 64; ++j) {
            float uj = ubuf[p][j];
            const float* wr = wbase + j * 512;  // uniform row -> s_load_dwordx16 x4
#pragma unroll
            for (int f = 0; f < 64; ++f)
                acc[f] = fmaf(uj, wr[f], acc[f]);
        }
        float* dst = a_t + pos;
#pragma unroll
        for (int f = 0; f < 64; ++f)
            dst[(size_t)(c * 64 + f) * N_FFT] = acc[f];   // lanes p: 256B coalesced
    }
}

// ========== conv: A-FFT (spectrum kept in regs) + z-FFT + mult + iFFT ==========
__global__ __launch_bounds__(FT, 2) void conv_kernel(const float* __restrict__ a_t,
                                                     const float2* __restrict__ xt2,
                                                     float2* __restrict__ out_t2)
{
    __shared__ float re[8448];
    __shared__ float im[8448];
    const int tid = threadIdx.x;
    const int hd = blockIdx.x;
    const float JR = 0.9238795325f;        // e^{-2pi i/16}
    const float JI = -0.3826834324f;

    // ---- A forward: fused m=8192 stage (real input) ----
    {
        const float* src = a_t + (size_t)hd * N_FFT;
        float ck, sk;
        __sincosf(-6.283185307179586f / 8192.f * (float)tid, &sk, &ck);
#pragma unroll
        for (int pp = 0; pp < 4; ++pp) {
            int k = pp * FT + tid;
            float x0 = src[k], x1 = src[k + 2048], x2 = src[k + 4096], x3 = src[k + 6144];
            float ar = x0 + x2, br = x0 - x2;
            float cr = x1 + x3, e = x1 - x3;
            re[PIDX(k)] = ar + cr; im[PIDX(k)] = 0.f;
            float c1 = ck, s1 = sk;
            float c2 = c1 * c1 - s1 * s1, s2 = 2.f * c1 * s1;
            float c3 = c2 * c1 - s2 * s1, s3 = c2 * s1 + s2 * c1;
            re[PIDX(k + 2048)] = br * c1 + e * s1;  im[PIDX(k + 2048)] = br * s1 - e * c1;
            float t2r = ar - cr;
            re[PIDX(k + 4096)] = t2r * c2;          im[PIDX(k + 4096)] = t2r * s2;
            re[PIDX(k + 6144)] = br * c3 - e * s3;  im[PIDX(k + 6144)] = br * s3 + e * c3;
            float tc = ck * JR - sk * JI; sk = ck * JI + sk * JR; ck = tc;  // W^{k+512}
        }
    }
    __syncthreads();
    pass16_fwd<2048>(re, im, tid);
    __syncthreads();
    pass16_fwd<128>(re, im, tid);
    __syncthreads();
    // ---- A tail: unscaled spectrum stays in registers (1/N folded in later) ----
    float afr[16], afi[16];
    {
        const int base = tid * 16;
#pragma unroll
        for (int c = 0; c < 16; ++c) { int idx = PIDX(base + c); afr[c] = re[idx]; afi[c] = im[idx]; }
        fwd8(afr, afi, 0); fwd8(afr, afi, 8);
    }
    __syncthreads();
    // ---- Z forward: fused m=8192 stage (packed complex, x2=x3=0) ----
    {
        const float2* src = xt2 + (size_t)hd * N_SEQ;
        float ck, sk;
        __sincosf(-6.283185307179586f / 8192.f * (float)tid, &sk, &ck);
#pragma unroll
        for (int pp = 0; pp < 4; ++pp) {
            int k = pp * FT + tid;
            float2 z0 = src[k], z1 = src[k + 2048];
            float ar = z0.x, ai = z0.y;
            float cr = z1.x, ci = z1.y;
            float dr = z1.y, di = -z1.x;
            re[PIDX(k)] = ar + cr; im[PIDX(k)] = ai + ci;
            float c1 = ck, s1 = sk;
            float c2 = c1 * c1 - s1 * s1, s2 = 2.f * c1 * s1;
            float c3 = c2 * c1 - s2 * s1, s3 = c2 * s1 + s2 * c1;
            float t1r = ar + dr, t1i = ai + di;
            re[PIDX(k + 2048)] = t1r * c1 - t1i * s1; im[PIDX(k + 2048)] = t1r * s1 + t1i * c1;
            float t2r = ar - cr, t2i = ai - ci;
            re[PIDX(k + 4096)] = t2r * c2 - t2i * s2; im[PIDX(k + 4096)] = t2r * s2 + t2i * c2;
            float t3r = ar - dr, t3i = ai - di;
            re[PIDX(k + 6144)] = t3r * c3 - t3i * s3; im[PIDX(k + 6144)] = t3r * s3 + t3i * c3;
            float tc = ck * JR - sk * JI; sk = ck * JI + sk * JR; ck = tc;
        }
    }
    __syncthreads();
    pass16_fwd<2048>(re, im, tid);
    __syncthreads();
    pass16_fwd<128>(re, im, tid);
    __syncthreads();
    {   // Z tail + pointwise (af in regs, 1/N fused) + inverse head
        const int base = tid * 16;
        float zr[16], zi[16];
#pragma unroll
        for (int c = 0; c < 16; ++c) { int idx = PIDX(base + c); zr[c] = re[idx]; zi[c] = im[idx]; }
        fwd8(zr, zi, 0); fwd8(zr, zi, 8);
        const float inv = 1.0f / (float)N_FFT;
#pragma unroll
        for (int c = 0; c < 16; ++c) {
            float xr = zr[c], xi_ = zi[c];
            zr[c] = (xr * afr[c] - xi_ * afi[c]) * inv;
            zi[c] = (xr * afi[c] + xi_ * afr[c]) * inv;
        }
        inv8(zr, zi, 0); inv8(zr, zi, 8);
#pragma unroll
        for (int c = 0; c < 16; ++c) { int idx = PIDX(base + c); re[idx] = zr[c]; im[idx] = zi[c]; }
    }
    __syncthreads();
    pass16_inv<128>(re, im, tid);
    __syncthreads();
    pass16_inv<2048>(re, im, tid);
    __syncthreads();
    {   // fused final inverse stage (m=8192): store only [0,4096)
        float2* dst = out_t2 + (size_t)hd * N_SEQ;
        float ck, sk;
        __sincosf(6.283185307179586f / 8192.f * (float)tid, &sk, &ck);
        const float JcR = 0.9238795325f, JcI = 0.3826834324f;
#pragma unroll
        for (int pp = 0; pp < 4; ++pp) {
            int k = pp * FT + tid;
            float c1 = ck, s1 = sk;
            float c2 = c1 * c1 - s1 * s1, s2 = 2.f * c1 * s1;
            float c3 = c2 * c1 - s2 * s1, s3 = c2 * s1 + s2 * c1;
            float t0r = re[PIDX(k)],        t0i = im[PIDX(k)];
            float y1r = re[PIDX(k + 2048)], y1i = im[PIDX(k + 2048)];
            float y2r = re[PIDX(k + 4096)], y2i = im[PIDX(k + 4096)];
            float y3r = re[PIDX(k + 6144)], y3i = im[PIDX(k + 6144)];
            float t1r = y1r * c1 - y1i * s1, t1i = y1r * s1 + y1i * c1;
            float t2r = y2r * c2 - y2i * s2, t2i = y2r * s2 + y2i * c2;
            float t3r = y3r * c3 - y3i * s3, t3i = y3r * s3 + y3i * c3;
            float pr = t0r + t2r, pi = t0i + t2i;
            float qr = t0r - t2r, qi = t0i - t2i;
            float rr = t1r + t3r, ri = t1i + t3i;
            float sr = -(t1i - t3i), si = t1r - t3r;
            dst[k]        = make_float2(pr + rr, pi + ri);
            dst[k + 2048] = make_float2(qr + sr, qi + si);
            float tc = ck * JcR - sk * JcI; sk = ck * JcI + sk * JcR; ck = tc;
        }
    }
}

// ========== transpose out: out_t2[hd][n] -> out (2,8,N,64) ==========
__global__ __launch_bounds__(256) void transpose_o_kernel(const float2* __restrict__ out_t2,
                                                          float* __restrict__ out)
{
    __shared__ float t0[64][65];
    __shared__ float t1[64][65];
    int h = blockIdx.x >> 6;
    int nb = blockIdx.x & 63;
    int lx = threadIdx.x & 63;
    int ly = threadIdx.x >> 6;
    for (int r = ly; r < 64; r += 4) {
        float2 v = out_t2[(size_t)(h * 64 + r) * N_SEQ + nb * 64 + lx];
        t0[r][lx] = v.x;
        t1[r][lx] = v.y;
    }
    __syncthreads();
    float* d0 = out + ((size_t)h * N_SEQ + nb * 64) * 64;
    float* d1 = out + ((size_t)(8 + h) * N_SEQ + nb * 64) * 64;
    for (int r = ly; r < 64; r += 4) {
        d0[r * 64 + lx] = t0[lx][r];
        d1[r * 64 + lx] = t1[lx][r];
    }
}

extern "C" void kernel_launch(void* const* d_in, const int* in_sizes, int n_in,
                              void* d_out, int out_size, void* d_ws, size_t ws_size,
                              hipStream_t stream)
{
    const float* x     = (const float*)d_in[0];
    const float* w_in  = (const float*)d_in[1];
    const float* b_in  = (const float*)d_in[2];
    const float* w_hid = (const float*)d_in[3];
    const float* b_hid = (const float*)d_in[4];
    const float* w_out = (const float*)d_in[5];
    const float* b_out = (const float*)d_in[6];
    float* out = (float*)d_out;

    char* ws = (char*)d_ws;
    float2* xt2    = (float2*)ws;                               // 16 MB
    float*  a_t    = (float*)(ws + (size_t)16 * 1024 * 1024);   // 16 MB
    float2* out_t2 = (float2*)(ws + (size_t)32 * 1024 * 1024);  // 16 MB

    prep_kernel<<<640, 512, 0, stream>>>(x, w_in, b_in, w_hid, b_hid, w_out, b_out,
                                         a_t, xt2);
    conv_kernel<<<512, FT, 0, stream>>>(a_t, xt2, out_t2);
    transpose_o_kernel<<<512, 256, 0, stream>>>(out_t2, out);
}